// Round 5
// baseline (117.586 us; speedup 1.0000x reference)
//
#include <hip/hip_runtime.h>

#define N_FEAT 1024
#define N_LAYER 4
#define R 4  // rows per wave: 4096 waves (16/CU) + 8KB/row weight amortization

typedef float floatx4 __attribute__((ext_vector_type(4)));  // native vec for nt-store

// Algebra: xi = A_i*x0 + C_i, C_i = sum_{j<i} b_j (row-independent).
//   p_i = <x0,w_i>, e_i = <C_i,w_i> (row-indep), A_{i+1} = A_i + A_i*p_i + e_i,
//   out = A_4*x0 + C_4.
// x0 is NOT kept in registers (saves 64 VGPRs -> stays under the 128-VGPR
// occupancy tier). The epilogue re-loads x from L2/L3 (just streamed, L3-hot)
// and uses non-temporal stores so `out` doesn't evict x from cache.
__global__ __launch_bounds__(256) void crossnet_kernel(
    const float* __restrict__ x,
    const float* __restrict__ weight_w,
    const float* __restrict__ weight_b,
    float* __restrict__ out,
    int n_rows) {
  const int wave = threadIdx.x >> 6;
  const int lane = threadIdx.x & 63;
  const int row0 = (blockIdx.x * 4 + wave) * R;
  if (row0 >= n_rows) return;

  const float4* xq = (const float4*)x;   // row stride = 256 float4
  floatx4* oq = (floatx4*)out;

  float p[R * N_LAYER];
#pragma unroll
  for (int k = 0; k < R * N_LAYER; ++k) p[k] = 0.f;
  float e[N_LAYER] = {0.f, 0.f, 0.f, 0.f};
  float4 csum[4];

  // ---- pass 1: per chunk, load w/b (L1-hot) + x (HBM), accumulate ----
#pragma unroll
  for (int c = 0; c < 4; ++c) {
    // issue the R x-loads first for ILP
    float4 xv[R];
#pragma unroll
    for (int r = 0; r < R; ++r)
      xv[r] = xq[(size_t)(row0 + r) * 256 + c * 64 + lane];

    float4 w[N_LAYER];
#pragma unroll
    for (int i = 0; i < N_LAYER; ++i)
      w[i] = ((const float4*)(weight_w + i * N_FEAT))[c * 64 + lane];

    float4 cum = make_float4(0.f, 0.f, 0.f, 0.f);
#pragma unroll
    for (int i = 0; i < N_LAYER; ++i) {
      if (i > 0)
        e[i] += cum.x * w[i].x + cum.y * w[i].y + cum.z * w[i].z + cum.w * w[i].w;
      float4 b = ((const float4*)(weight_b + i * N_FEAT))[c * 64 + lane];
      cum.x += b.x; cum.y += b.y; cum.z += b.z; cum.w += b.w;
    }
    csum[c] = cum;

#pragma unroll
    for (int r = 0; r < R; ++r) {
#pragma unroll
      for (int i = 0; i < N_LAYER; ++i) {
        p[r * N_LAYER + i] += xv[r].x * w[i].x + xv[r].y * w[i].y +
                              xv[r].z * w[i].z + xv[r].w * w[i].w;
      }
    }
  }

  // ---- single butterfly: 19 independent values, 6 steps ----
#pragma unroll
  for (int off = 32; off > 0; off >>= 1) {
#pragma unroll
    for (int k = 0; k < R * N_LAYER; ++k) p[k] += __shfl_xor(p[k], off, 64);
#pragma unroll
    for (int i = 1; i < N_LAYER; ++i) e[i] += __shfl_xor(e[i], off, 64);
  }

  // ---- per-row scalar recurrence ----
  float A[R];
#pragma unroll
  for (int r = 0; r < R; ++r) {
    float a = 1.f;
#pragma unroll
    for (int i = 0; i < N_LAYER; ++i)
      a += a * p[r * N_LAYER + i] + e[i];
    A[r] = a;
  }

  // ---- epilogue: re-load x (L2/L3-hot), fuse, non-temporal store ----
#pragma unroll
  for (int r = 0; r < R; ++r) {
#pragma unroll
    for (int c = 0; c < 4; ++c) {
      const size_t idx = (size_t)(row0 + r) * 256 + c * 64 + lane;
      float4 xv = xq[idx];
      floatx4 o;
      o.x = fmaf(xv.x, A[r], csum[c].x);
      o.y = fmaf(xv.y, A[r], csum[c].y);
      o.z = fmaf(xv.z, A[r], csum[c].z);
      o.w = fmaf(xv.w, A[r], csum[c].w);
      __builtin_nontemporal_store(o, &oq[idx]);
    }
  }
}

extern "C" void kernel_launch(void* const* d_in, const int* in_sizes, int n_in,
                              void* d_out, int out_size, void* d_ws, size_t ws_size,
                              hipStream_t stream) {
  const float* x = (const float*)d_in[0];
  const float* ww = (const float*)d_in[1];
  const float* wb = (const float*)d_in[2];
  float* out = (float*)d_out;

  int n_rows = in_sizes[0] / N_FEAT;                 // 16384
  int rows_per_block = 4 * R;                        // 4 waves x 4 rows
  int n_blocks = (n_rows + rows_per_block - 1) / rows_per_block;  // 1024
  crossnet_kernel<<<n_blocks, 256, 0, stream>>>(x, ww, wb, out, n_rows);
}